// Round 6
// baseline (390.625 us; speedup 1.0000x reference)
//
#include <hip/hip_runtime.h>
#include <math.h>

#define NN 20000
#define HEADS 8
#define GDIM 1024
#define M_PAD 20096   // 157 * 128

typedef _Float16 f16;
typedef f16 f16x2  __attribute__((ext_vector_type(2)));
typedef f16 f16x4v __attribute__((ext_vector_type(4)));
typedef f16 f16x8v __attribute__((ext_vector_type(8)));
typedef float f32x4 __attribute__((ext_vector_type(4)));

// ---------- helpers ----------
__device__ __forceinline__ float lrelu(float x){ return x > 0.f ? x : 0.2f*x; }

// ---------- init: zero scratch ints + weight transpose/convert fp32[K][N] -> f16[N][K] ----------
__global__ __launch_bounds__(256) void init_k(int* __restrict__ zbase, int zn,
        const float* __restrict__ W1, const float* __restrict__ W2, const float* __restrict__ W3,
        const float* __restrict__ Wg, const float* __restrict__ Wh1,
        f16* __restrict__ wt1, f16* __restrict__ wt2, f16* __restrict__ wt3,
        f16* __restrict__ wtg, f16* __restrict__ wth1)
{
    int t = blockIdx.x*256 + threadIdx.x;
    if (t < zn){ zbase[t] = 0; return; }
    t -= zn;
    if (t < 65536){ int k = t >> 8, n = t & 255; wt1[n*256 + k] = (f16)W1[t]; return; }
    t -= 65536;
    if (t < 65536){ int k = t >> 8, n = t & 255; wt2[n*256 + k] = (f16)W2[t]; return; }
    t -= 65536;
    if (t < 32768){ int k = t >> 7, n = t & 127; wt3[n*256 + k] = (f16)W3[t]; return; }
    t -= 32768;
    if (t < 131072){ int k = t >> 10, n = t & 1023; wtg[n*128 + k] = (f16)Wg[t]; return; }
    t -= 131072;
    if (t < 262144){ int k = t >> 8, n = t & 255; wth1[n*1024 + k] = (f16)Wh1[t]; return; }
}

// ---------- CSR build ----------
__global__ __launch_bounds__(256) void hist_k(const int* __restrict__ dst, int* __restrict__ cnt, int E){
    int i = blockIdx.x*256 + threadIdx.x;
    if (i < E) atomicAdd(&cnt[dst[i]], 1);
}
__global__ __launch_bounds__(1024) void scan_k(const int* __restrict__ cnt, int* __restrict__ row_off,
                                               float* __restrict__ dinv){
    __shared__ int tot[1024];
    int t = threadIdx.x;
    const int CH = 20;
    int base = t*CH;
    int loc[CH]; int s = 0;
    #pragma unroll
    for (int i = 0; i < CH; ++i){
        int v = (base+i < NN) ? cnt[base+i] : 0;
        loc[i] = s; s += v;
    }
    tot[t] = s; __syncthreads();
    for (int off = 1; off < 1024; off <<= 1){
        int v = (t >= off) ? tot[t-off] : 0;
        __syncthreads();
        tot[t] += v;
        __syncthreads();
    }
    int pre = (t == 0) ? 0 : tot[t-1];
    #pragma unroll
    for (int i = 0; i < CH; ++i)
        if (base+i < NN){
            row_off[base+i] = pre + loc[i];
            dinv[base+i] = rsqrtf((float)cnt[base+i] + 1.f);
        }
    if (t == 1023) row_off[NN] = tot[1023];
}
__global__ __launch_bounds__(256) void scatter_k(const int* __restrict__ src, const int* __restrict__ dst,
        const int* __restrict__ row_off, int* __restrict__ cursor, int* __restrict__ src_sorted, int E){
    int i = blockIdx.x*256 + threadIdx.x;
    if (i >= E) return;
    int d = dst[i];
    int pos = row_off[d] + atomicAdd(&cursor[d], 1);
    src_sorted[pos] = src[i];
}

// ---------- fp16 MFMA GEMM: C[M,N] = A[M,K] @ Bt[N,K]^T ----------
// 128x128 tile, BK=32, 4 waves (2x2), each wave 64x64 via 4x4 mfma_16x16x32_f16.
// EPI: 0 = store f16 C; 1 = store f16 C + per-(row,head) att dots; 2 = head (no C store,
//      logit[row] += sum_col relu(acc+bias)*Wh2[col] via atomics).
template<int EPI, bool A_F32, bool RELU, bool HAS_BIAS>
__global__ __launch_bounds__(256,2) void gemm_f16_k(
        const void* __restrict__ Av, const f16* __restrict__ Bt,
        const float* __restrict__ bias, void* __restrict__ C,
        const float* __restrict__ att_s, const float* __restrict__ att_d,
        float* __restrict__ as_out, float* __restrict__ ad_out,
        const float* __restrict__ Wh2, float* __restrict__ logit,
        int M, int N, int K)
{
    __shared__ __align__(16) f16 As[128*32];
    __shared__ __align__(16) f16 Bs[128*32];
    __shared__ float sred[2][128][2];
    const int tid  = threadIdx.x;
    const int lane = tid & 63;
    const int wave = tid >> 6;
    const int wm = (wave >> 1) * 64, wn = (wave & 1) * 64;
    const int l15 = lane & 15, quad = lane >> 4;
    const int m0 = blockIdx.y * 128, n0 = blockIdx.x * 128;

    const int r1 = tid >> 2;
    const int ce = (tid & 3) * 8;          // element offset within 32-elem K-chunk
    const int rowA0 = m0 + r1, rowA1 = rowA0 + 64;
    const f16*  Ah = (const f16*)Av;
    const float* Af = (const float*)Av;
    const f16* B0 = Bt + (size_t)(n0 + r1) * K + ce;
    const f16* B1 = B0 + (size_t)64 * K;

    f32x4 acc[4][4] = {};
    for (int k0 = 0; k0 < K; k0 += 32){
        if (A_F32){
            f16x8v h0 = {}, h1 = {};
            if (rowA0 < M){
                float4 p = *(const float4*)(Af + (size_t)rowA0*K + k0 + ce);
                float4 q = *(const float4*)(Af + (size_t)rowA0*K + k0 + ce + 4);
                h0[0]=(f16)p.x; h0[1]=(f16)p.y; h0[2]=(f16)p.z; h0[3]=(f16)p.w;
                h0[4]=(f16)q.x; h0[5]=(f16)q.y; h0[6]=(f16)q.z; h0[7]=(f16)q.w;
            }
            if (rowA1 < M){
                float4 p = *(const float4*)(Af + (size_t)rowA1*K + k0 + ce);
                float4 q = *(const float4*)(Af + (size_t)rowA1*K + k0 + ce + 4);
                h1[0]=(f16)p.x; h1[1]=(f16)p.y; h1[2]=(f16)p.z; h1[3]=(f16)p.w;
                h1[4]=(f16)q.x; h1[5]=(f16)q.y; h1[6]=(f16)q.z; h1[7]=(f16)q.w;
            }
            *(f16x8v*)&As[tid*8]        = h0;
            *(f16x8v*)&As[tid*8 + 2048] = h1;
        } else {
            *(uint4*)&As[tid*8]        = *(const uint4*)(Ah + (size_t)rowA0*K + k0 + ce);
            *(uint4*)&As[tid*8 + 2048] = *(const uint4*)(Ah + (size_t)rowA1*K + k0 + ce);
        }
        *(uint4*)&Bs[tid*8]        = *(const uint4*)(B0 + k0);
        *(uint4*)&Bs[tid*8 + 2048] = *(const uint4*)(B1 + k0);
        __syncthreads();
        f16x8v af[4], bf[4];
        #pragma unroll
        for (int i = 0; i < 4; ++i){
            af[i] = *(const f16x8v*)&As[(wm + i*16 + l15)*32 + quad*8];
            bf[i] = *(const f16x8v*)&Bs[(wn + i*16 + l15)*32 + quad*8];
        }
        #pragma unroll
        for (int i = 0; i < 4; ++i)
            #pragma unroll
            for (int j = 0; j < 4; ++j)
                acc[i][j] = __builtin_amdgcn_mfma_f32_16x16x32_f16(af[i], bf[j], acc[i][j], 0, 0, 0);
        __syncthreads();
    }

    if (EPI == 2){
        float b4[4], w4[4];
        #pragma unroll
        for (int j = 0; j < 4; ++j){
            int cg = n0 + wn + j*16 + l15;
            b4[j] = bias[cg]; w4[j] = Wh2[cg];
        }
        #pragma unroll
        for (int i = 0; i < 4; ++i)
            #pragma unroll
            for (int r = 0; r < 4; ++r){
                float ps = 0.f;
                #pragma unroll
                for (int j = 0; j < 4; ++j){
                    float v = fmaxf(acc[i][j][r] + b4[j], 0.f);
                    ps = fmaf(v, w4[j], ps);
                }
                ps += __shfl_xor(ps, 1, 64); ps += __shfl_xor(ps, 2, 64);
                ps += __shfl_xor(ps, 4, 64); ps += __shfl_xor(ps, 8, 64);
                if (l15 == 0){
                    int row = m0 + wm + i*16 + quad*4 + r;
                    if (row < M) unsafeAtomicAdd(&logit[row], ps);
                }
            }
        return;
    }

    // store C (f16)
    #pragma unroll
    for (int i = 0; i < 4; ++i){
        int rb = m0 + wm + i*16 + quad*4;
        #pragma unroll
        for (int j = 0; j < 4; ++j){
            int col = n0 + wn + j*16 + l15;
            float bv = HAS_BIAS ? bias[col] : 0.f;
            #pragma unroll
            for (int r = 0; r < 4; ++r){
                int row = rb + r;
                if (row >= M) continue;
                float v = acc[i][j][r] + bv;
                if (RELU) v = fmaxf(v, 0.f);
                ((f16*)C)[(size_t)row*N + col] = (f16)v;
            }
        }
    }

    if (EPI == 1){
        const int h = blockIdx.x;
        float ats[4], atd[4];
        #pragma unroll
        for (int j = 0; j < 4; ++j){
            int c = wn + j*16 + l15;
            ats[j] = att_s[h*128 + c]; atd[j] = att_d[h*128 + c];
        }
        #pragma unroll
        for (int i = 0; i < 4; ++i)
            #pragma unroll
            for (int r = 0; r < 4; ++r){
                float ps = 0.f, pd = 0.f;
                #pragma unroll
                for (int j = 0; j < 4; ++j){
                    float a = acc[i][j][r];
                    ps = fmaf(a, ats[j], ps); pd = fmaf(a, atd[j], pd);
                }
                ps += __shfl_xor(ps, 1, 64); ps += __shfl_xor(ps, 2, 64);
                ps += __shfl_xor(ps, 4, 64); ps += __shfl_xor(ps, 8, 64);
                pd += __shfl_xor(pd, 1, 64); pd += __shfl_xor(pd, 2, 64);
                pd += __shfl_xor(pd, 4, 64); pd += __shfl_xor(pd, 8, 64);
                if (l15 == 0){
                    int rl = wm + i*16 + quad*4 + r;
                    sred[0][rl][wn >> 6] = ps;
                    sred[1][rl][wn >> 6] = pd;
                }
            }
        __syncthreads();
        if (tid < 128){
            int row = m0 + tid;
            if (row < M){
                as_out[row*HEADS + h] = sred[0][tid][0] + sred[0][tid][1];
                ad_out[row*HEADS + h] = sred[1][tid][0] + sred[1][tid][1];
            }
        }
    }
}

// ---------- GCN aggregation (fp16 in/out, fp32 acc): fused self + bias + relu, 4-edge unroll ----------
template<int F>   // 256 or 128
__global__ __launch_bounds__(256) void gcn_agg_f16_k(const f16* __restrict__ h, const int* __restrict__ row_off,
        const int* __restrict__ srcs, const float* __restrict__ dinv, const float* __restrict__ bias,
        f16* __restrict__ out)
{
    int wv = (blockIdx.x*256 + threadIdx.x) >> 6;
    int lane = threadIdx.x & 63;
    if (wv >= NN) return;
    float di = dinv[wv];
    int p = row_off[wv], r1 = row_off[wv+1];
    if (F == 256){
        f16x4v v = *(const f16x4v*)(h + (size_t)wv*256 + lane*4);
        float c = di*di;
        float a0 = (float)v[0]*c, a1 = (float)v[1]*c, a2 = (float)v[2]*c, a3 = (float)v[3]*c;
        for (; p+4 <= r1; p += 4){
            int s0 = srcs[p], s1 = srcs[p+1], s2 = srcs[p+2], s3 = srcs[p+3];
            float c0 = dinv[s0]*di, c1 = dinv[s1]*di, c2 = dinv[s2]*di, c3 = dinv[s3]*di;
            f16x4v u0 = *(const f16x4v*)(h + (size_t)s0*256 + lane*4);
            f16x4v u1 = *(const f16x4v*)(h + (size_t)s1*256 + lane*4);
            f16x4v u2 = *(const f16x4v*)(h + (size_t)s2*256 + lane*4);
            f16x4v u3 = *(const f16x4v*)(h + (size_t)s3*256 + lane*4);
            a0 = fmaf((float)u3[0], c3, fmaf((float)u2[0], c2, fmaf((float)u1[0], c1, fmaf((float)u0[0], c0, a0))));
            a1 = fmaf((float)u3[1], c3, fmaf((float)u2[1], c2, fmaf((float)u1[1], c1, fmaf((float)u0[1], c0, a1))));
            a2 = fmaf((float)u3[2], c3, fmaf((float)u2[2], c2, fmaf((float)u1[2], c1, fmaf((float)u0[2], c0, a2))));
            a3 = fmaf((float)u3[3], c3, fmaf((float)u2[3], c2, fmaf((float)u1[3], c1, fmaf((float)u0[3], c0, a3))));
        }
        for (; p < r1; ++p){
            int s0 = srcs[p];
            float c0 = dinv[s0]*di;
            f16x4v u0 = *(const f16x4v*)(h + (size_t)s0*256 + lane*4);
            a0 = fmaf((float)u0[0], c0, a0); a1 = fmaf((float)u0[1], c0, a1);
            a2 = fmaf((float)u0[2], c0, a2); a3 = fmaf((float)u0[3], c0, a3);
        }
        float4 bv = *(const float4*)(bias + lane*4);
        f16x4v o;
        o[0] = (f16)fmaxf(a0 + bv.x, 0.f); o[1] = (f16)fmaxf(a1 + bv.y, 0.f);
        o[2] = (f16)fmaxf(a2 + bv.z, 0.f); o[3] = (f16)fmaxf(a3 + bv.w, 0.f);
        __builtin_nontemporal_store(o, (f16x4v*)(out + (size_t)wv*256 + lane*4));
    } else {
        f16x2 v = *(const f16x2*)(h + (size_t)wv*128 + lane*2);
        float c = di*di;
        float a0 = (float)v[0]*c, a1 = (float)v[1]*c;
        for (; p+4 <= r1; p += 4){
            int s0 = srcs[p], s1 = srcs[p+1], s2 = srcs[p+2], s3 = srcs[p+3];
            float c0 = dinv[s0]*di, c1 = dinv[s1]*di, c2 = dinv[s2]*di, c3 = dinv[s3]*di;
            f16x2 u0 = *(const f16x2*)(h + (size_t)s0*128 + lane*2);
            f16x2 u1 = *(const f16x2*)(h + (size_t)s1*128 + lane*2);
            f16x2 u2 = *(const f16x2*)(h + (size_t)s2*128 + lane*2);
            f16x2 u3 = *(const f16x2*)(h + (size_t)s3*128 + lane*2);
            a0 = fmaf((float)u3[0], c3, fmaf((float)u2[0], c2, fmaf((float)u1[0], c1, fmaf((float)u0[0], c0, a0))));
            a1 = fmaf((float)u3[1], c3, fmaf((float)u2[1], c2, fmaf((float)u1[1], c1, fmaf((float)u0[1], c0, a1))));
        }
        for (; p < r1; ++p){
            int s0 = srcs[p];
            float c0 = dinv[s0]*di;
            f16x2 u0 = *(const f16x2*)(h + (size_t)s0*128 + lane*2);
            a0 = fmaf((float)u0[0], c0, a0); a1 = fmaf((float)u0[1], c0, a1);
        }
        float2 bv = *(const float2*)(bias + lane*2);
        f16x2 o;
        o[0] = (f16)fmaxf(a0 + bv.x, 0.f); o[1] = (f16)fmaxf(a1 + bv.y, 0.f);
        __builtin_nontemporal_store(o, (f16x2*)(out + (size_t)wv*128 + lane*2));
    }
}

// ---------- GAT softmax over CSR ----------
__global__ __launch_bounds__(256) void gat_soft_k(const int* __restrict__ row_off, const int* __restrict__ srcs,
        const float* __restrict__ a_s, const float* __restrict__ a_d,
        float* __restrict__ ex_sorted, float* __restrict__ alpha_self, float* __restrict__ inv_den)
{
    int t = blockIdx.x*256 + threadIdx.x;
    if (t >= NN*HEADS) return;
    int d = t >> 3, h = t & 7;
    float ad = a_d[t];
    float eself = lrelu(a_s[t] + ad);
    float m = eself;
    int r0 = row_off[d], r1 = row_off[d+1];
    for (int p = r0; p < r1; ++p){
        int s = srcs[p];
        m = fmaxf(m, lrelu(a_s[s*HEADS + h] + ad));
    }
    float den = expf(eself - m);
    for (int p = r0; p < r1; ++p){
        int s = srcs[p];
        float x = expf(lrelu(a_s[s*HEADS + h] + ad) - m);
        ex_sorted[(size_t)p*HEADS + h] = x;
        den += x;
    }
    float id = 1.f / den;
    alpha_self[t] = expf(eself - m) * id;
    inv_den[t]    = id;
}
// per (dst, half): gat[d, half*512 + :512] — 2 waves per node, 4-edge unroll, nt store
__global__ __launch_bounds__(256) void gat_out_f16_k(const f16* __restrict__ hg, const int* __restrict__ row_off,
        const int* __restrict__ srcs, const float* __restrict__ exs, const float* __restrict__ aself,
        const float* __restrict__ idn, const float* __restrict__ bg, f16* __restrict__ gat)
{
    int gw = (blockIdx.x*256 + threadIdx.x) >> 6;   // over 2*NN
    int lane = threadIdx.x & 63;
    int node = gw >> 1;
    if (node >= NN) return;
    int colbase = (gw & 1)*512 + lane*8;
    int hh = colbase >> 7;
    int nh = node*HEADS + hh;
    float as = aself[nh];
    float id = idn[nh];
    const f16* table = hg + colbase;
    f16x8v v = *(const f16x8v*)(table + (size_t)node*GDIM);
    float acc[8];
    #pragma unroll
    for (int q = 0; q < 8; ++q) acc[q] = (float)v[q]*as;
    int p = row_off[node], r1 = row_off[node+1];
    for (; p+4 <= r1; p += 4){
        int s0 = srcs[p], s1 = srcs[p+1], s2 = srcs[p+2], s3 = srcs[p+3];
        float al0 = exs[(size_t)p*HEADS + hh] * id;
        float al1 = exs[(size_t)(p+1)*HEADS + hh] * id;
        float al2 = exs[(size_t)(p+2)*HEADS + hh] * id;
        float al3 = exs[(size_t)(p+3)*HEADS + hh] * id;
        f16x8v u0 = *(const f16x8v*)(table + (size_t)s0*GDIM);
        f16x8v u1 = *(const f16x8v*)(table + (size_t)s1*GDIM);
        f16x8v u2 = *(const f16x8v*)(table + (size_t)s2*GDIM);
        f16x8v u3 = *(const f16x8v*)(table + (size_t)s3*GDIM);
        #pragma unroll
        for (int q = 0; q < 8; ++q)
            acc[q] = fmaf((float)u3[q], al3, fmaf((float)u2[q], al2,
                     fmaf((float)u1[q], al1, fmaf((float)u0[q], al0, acc[q]))));
    }
    for (; p < r1; ++p){
        int s0 = srcs[p];
        float al0 = exs[(size_t)p*HEADS + hh] * id;
        f16x8v u0 = *(const f16x8v*)(table + (size_t)s0*GDIM);
        #pragma unroll
        for (int q = 0; q < 8; ++q) acc[q] = fmaf((float)u0[q], al0, acc[q]);
    }
    float4 b0 = *(const float4*)(bg + colbase);
    float4 b1 = *(const float4*)(bg + colbase + 4);
    f16x8v o;
    o[0]=(f16)(acc[0]+b0.x); o[1]=(f16)(acc[1]+b0.y); o[2]=(f16)(acc[2]+b0.z); o[3]=(f16)(acc[3]+b0.w);
    o[4]=(f16)(acc[4]+b1.x); o[5]=(f16)(acc[5]+b1.y); o[6]=(f16)(acc[6]+b1.z); o[7]=(f16)(acc[7]+b1.w);
    __builtin_nontemporal_store(o, (f16x8v*)(gat + (size_t)node*GDIM + colbase));
}

// ---------- head: sigmoid + global exp-sum (no max pass needed: w in (0,1)) ----------
__global__ __launch_bounds__(256) void head_sum_k(const float* __restrict__ logit, const float* __restrict__ bh2,
                                                  float* __restrict__ w, float* __restrict__ red){
    __shared__ float sm[256];
    int i = blockIdx.x*256 + threadIdx.x;
    float v = 0.f;
    if (i < NN){
        float s = 1.f / (1.f + expf(-(logit[i] + bh2[0])));
        w[i] = s;
        v = expf(s);
    }
    sm[threadIdx.x] = v; __syncthreads();
    for (int off = 128; off; off >>= 1){
        if (threadIdx.x < off) sm[threadIdx.x] += sm[threadIdx.x+off];
        __syncthreads();
    }
    if (!threadIdx.x) unsafeAtomicAdd(&red[0], sm[0]);
}
__global__ __launch_bounds__(256) void final_k(const float* __restrict__ w, const float* __restrict__ red,
                                               float* __restrict__ out){
    int i = blockIdx.x*256 + threadIdx.x;
    if (i >= NN) return;
    out[i] = expf(w[i]) / red[0];
}

// ---------- launch ----------
extern "C" void kernel_launch(void* const* d_in, const int* in_sizes, int n_in,
                              void* d_out, int out_size, void* d_ws, size_t ws_size,
                              hipStream_t stream) {
    const float* x   = (const float*)d_in[0];
    const int*   ei  = (const int*)  d_in[1];
    const float* W1  = (const float*)d_in[2];
    const float* b1  = (const float*)d_in[3];
    const float* W2  = (const float*)d_in[4];
    const float* b2  = (const float*)d_in[5];
    const float* W3  = (const float*)d_in[6];
    const float* b3  = (const float*)d_in[7];
    const float* Wg  = (const float*)d_in[8];
    const float* att_src = (const float*)d_in[9];
    const float* att_dst = (const float*)d_in[10];
    const float* bg  = (const float*)d_in[11];
    const float* Wh1 = (const float*)d_in[12];
    const float* bh1 = (const float*)d_in[13];
    const float* Wh2 = (const float*)d_in[14];
    const float* bh2 = (const float*)d_in[15];
    float* out = (float*)d_out;

    const int E = in_sizes[1] / 2;
    const int* src = ei;
    const int* dst = ei + E;

    float* ws = (float*)d_ws;
    size_t o = 0;
    auto alloc = [&](size_t nfloats){ float* p = ws + o; o += (nfloats + 3) & ~(size_t)3; return p; };
    // zero region: cnt, cursor, logit, red contiguous
    int* cnt    = (int*)alloc(NN);
    int* cursor = (int*)alloc(NN);
    float* logit= alloc(NN);
    float* red  = alloc(8);
    const int ZERO_N = 3*NN + 8;

    f16* wt1   = (f16*)alloc(65536/2);
    f16* wt2   = (f16*)alloc(65536/2);
    f16* wt3   = (f16*)alloc(32768/2);
    f16* wtg   = (f16*)alloc(131072/2);
    f16* wth1  = (f16*)alloc(262144/2);
    f16* fH    = (f16*)alloc((size_t)M_PAD*256/2);
    f16* fG    = (f16*)alloc((size_t)M_PAD*256/2);
    f16* hg    = (f16*)alloc((size_t)M_PAD*GDIM/2);
    f16* gat   = (f16*)alloc((size_t)M_PAD*GDIM/2);
    float* dinv = alloc(NN);
    float* a_s  = alloc((size_t)NN*HEADS);
    float* a_d  = alloc((size_t)NN*HEADS);
    float* aself= alloc((size_t)NN*HEADS);
    float* idn  = alloc((size_t)NN*HEADS);
    float* exs  = alloc((size_t)E*HEADS);
    float* wsig = alloc(NN);
    int* row_off= (int*)alloc(NN+1);
    int* src_srt= (int*)alloc(E);

    const int nb  = (NN + 255)/256;
    const int eb  = (E + 255)/256;
    const int nwb = (NN + 3)/4;
    const dim3 blk(256);
    const int MT = M_PAD/128;   // 157

    // init (zero + weight cvt), CSR, dinv
    const int INIT_T = ZERO_N + 65536*2 + 32768 + 131072 + 262144;
    init_k<<<(INIT_T + 255)/256, blk, 0, stream>>>(cnt, ZERO_N, W1, W2, W3, Wg, Wh1,
                                                   wt1, wt2, wt3, wtg, wth1);
    hist_k<<<eb, blk, 0, stream>>>(dst, cnt, E);
    scan_k<<<1, 1024, 0, stream>>>(cnt, row_off, dinv);
    scatter_k<<<eb, blk, 0, stream>>>(src, dst, row_off, cursor, src_srt, E);

    // GCN 1: A = x (fp32, read directly)
    gemm_f16_k<0,true,false,false><<<dim3(2, MT), blk, 0, stream>>>(
        x, wt1, nullptr, fH, nullptr, nullptr, nullptr, nullptr, nullptr, nullptr, NN, 256, 256);
    gcn_agg_f16_k<256><<<nwb, blk, 0, stream>>>(fH, row_off, src_srt, dinv, b1, fG);
    // GCN 2
    gemm_f16_k<0,false,false,false><<<dim3(2, MT), blk, 0, stream>>>(
        fG, wt2, nullptr, fH, nullptr, nullptr, nullptr, nullptr, nullptr, nullptr, NN, 256, 256);
    gcn_agg_f16_k<256><<<nwb, blk, 0, stream>>>(fH, row_off, src_srt, dinv, b2, fG);
    // GCN 3 (N=128)
    gemm_f16_k<0,false,false,false><<<dim3(1, MT), blk, 0, stream>>>(
        fG, wt3, nullptr, fH, nullptr, nullptr, nullptr, nullptr, nullptr, nullptr, NN, 128, 256);
    gcn_agg_f16_k<128><<<nwb, blk, 0, stream>>>(fH, row_off, src_srt, dinv, b3, fG);

    // GAT projection (K=128, N=1024) + fused att dots
    gemm_f16_k<1,false,false,false><<<dim3(8, MT), blk, 0, stream>>>(
        fG, wtg, nullptr, hg, att_src, att_dst, a_s, a_d, nullptr, nullptr, NN, 1024, 128);
    gat_soft_k<<<(NN*HEADS)/256, blk, 0, stream>>>(row_off, src_srt, a_s, a_d, exs, aself, idn);
    gat_out_f16_k<<<NN/2, blk, 0, stream>>>(hg, row_off, src_srt, exs, aself, idn, bg, gat);

    // head MLP (K=1024, N=256): fused relu(z)@Wh2 -> logit atomics
    gemm_f16_k<2,false,true,true><<<dim3(2, MT), blk, 0, stream>>>(
        gat, wth1, bh1, nullptr, nullptr, nullptr, nullptr, nullptr, Wh2, logit, NN, 256, 1024);

    // sigmoid + global softmax (no max pass: w bounded in (0,1))
    head_sum_k<<<nb, blk, 0, stream>>>(logit, bh2, wsig, red);
    final_k<<<nb, blk, 0, stream>>>(wsig, red, out);
}

// Round 8
// 374.409 us; speedup vs baseline: 1.0433x; 1.0433x over previous
//
#include <hip/hip_runtime.h>
#include <math.h>

#define NN 20000
#define HEADS 8
#define GDIM 1024
#define M_PAD 20096   // 157 * 128

typedef _Float16 f16;
typedef f16 f16x2  __attribute__((ext_vector_type(2)));
typedef f16 f16x4v __attribute__((ext_vector_type(4)));
typedef f16 f16x8v __attribute__((ext_vector_type(8)));
typedef float f32x4 __attribute__((ext_vector_type(4)));

// ---------- helpers ----------
__device__ __forceinline__ float lrelu(float x){ return x > 0.f ? x : 0.2f*x; }

// ---------- init: zero scratch ints + weight transpose/convert fp32[K][N] -> f16[N][K] ----------
__global__ __launch_bounds__(256) void init_k(int* __restrict__ zbase, int zn,
        const float* __restrict__ W1, const float* __restrict__ W2, const float* __restrict__ W3,
        const float* __restrict__ Wg, const float* __restrict__ Wh1,
        f16* __restrict__ wt1, f16* __restrict__ wt2, f16* __restrict__ wt3,
        f16* __restrict__ wtg, f16* __restrict__ wth1)
{
    int t = blockIdx.x*256 + threadIdx.x;
    if (t < zn){ zbase[t] = 0; return; }
    t -= zn;
    if (t < 65536){ int k = t >> 8, n = t & 255; wt1[n*256 + k] = (f16)W1[t]; return; }
    t -= 65536;
    if (t < 65536){ int k = t >> 8, n = t & 255; wt2[n*256 + k] = (f16)W2[t]; return; }
    t -= 65536;
    if (t < 32768){ int k = t >> 7, n = t & 127; wt3[n*256 + k] = (f16)W3[t]; return; }
    t -= 32768;
    if (t < 131072){ int k = t >> 10, n = t & 1023; wtg[n*128 + k] = (f16)Wg[t]; return; }
    t -= 131072;
    if (t < 262144){ int k = t >> 8, n = t & 255; wth1[n*1024 + k] = (f16)Wh1[t]; return; }
}

// ---------- CSR build ----------
__global__ __launch_bounds__(256) void hist_k(const int* __restrict__ dst, int* __restrict__ cnt, int E){
    int i = blockIdx.x*256 + threadIdx.x;
    if (i < E) atomicAdd(&cnt[dst[i]], 1);
}
__global__ __launch_bounds__(1024) void scan_k(const int* __restrict__ cnt, int* __restrict__ row_off,
                                               float* __restrict__ dinv){
    __shared__ int tot[1024];
    int t = threadIdx.x;
    const int CH = 20;
    int base = t*CH;
    int loc[CH]; int s = 0;
    #pragma unroll
    for (int i = 0; i < CH; ++i){
        int v = (base+i < NN) ? cnt[base+i] : 0;
        loc[i] = s; s += v;
    }
    tot[t] = s; __syncthreads();
    for (int off = 1; off < 1024; off <<= 1){
        int v = (t >= off) ? tot[t-off] : 0;
        __syncthreads();
        tot[t] += v;
        __syncthreads();
    }
    int pre = (t == 0) ? 0 : tot[t-1];
    #pragma unroll
    for (int i = 0; i < CH; ++i)
        if (base+i < NN){
            row_off[base+i] = pre + loc[i];
            dinv[base+i] = rsqrtf((float)cnt[base+i] + 1.f);
        }
    if (t == 1023) row_off[NN] = tot[1023];
}
__global__ __launch_bounds__(256) void scatter_k(const int* __restrict__ src, const int* __restrict__ dst,
        const int* __restrict__ row_off, int* __restrict__ cursor, int* __restrict__ src_sorted, int E){
    int i = blockIdx.x*256 + threadIdx.x;
    if (i >= E) return;
    int d = dst[i];
    int pos = row_off[d] + atomicAdd(&cursor[d], 1);
    src_sorted[pos] = src[i];
}

// ---------- fp16 MFMA GEMM: C[M,N] = A[M,K] @ Bt[N,K]^T ----------
// BM=128 fixed, BN in {64,128}, BK=32, 4 waves (2x2), wave covers 64 x BN/2.
// EPI: 0 = store f16 C; 1 = store f16 C + per-(row,head) att dots (BN=128 only);
//      2 = logit[row] += sum_col relu(acc+bias)*Wh2[col] via atomics (FULL K only —
//          relu is nonlinear, split-K would be wrong).
template<int EPI, int BN, bool A_F32, bool RELU, bool HAS_BIAS>
__global__ __launch_bounds__(256,2) void gemm_f16_k(
        const void* __restrict__ Av, const f16* __restrict__ Bt,
        const float* __restrict__ bias, void* __restrict__ C,
        const float* __restrict__ att_s, const float* __restrict__ att_d,
        float* __restrict__ as_out, float* __restrict__ ad_out,
        const float* __restrict__ Wh2, float* __restrict__ logit,
        int M, int N, int K)
{
    constexpr int WN = BN/2;
    constexpr int NJ = WN/16;
    __shared__ __align__(16) f16 As[128*32];
    __shared__ __align__(16) f16 Bs[BN*32];
    __shared__ float sred[2][128][2];
    const int tid  = threadIdx.x;
    const int lane = tid & 63;
    const int wave = tid >> 6;
    const int wm = (wave >> 1) * 64, wn = (wave & 1) * WN;
    const int l15 = lane & 15, quad = lane >> 4;
    const int m0 = blockIdx.y * 128, n0 = blockIdx.x * BN;

    const int r1 = tid >> 2;
    const int ce = (tid & 3) * 8;          // element offset within 32-elem K-chunk
    const int rowA0 = m0 + r1, rowA1 = rowA0 + 64;
    const f16*  Ah = (const f16*)Av;
    const float* Af = (const float*)Av;
    const f16* B0 = Bt + (size_t)(n0 + r1) * K + ce;
    const f16* B1 = B0 + (size_t)64 * K;

    f32x4 acc[4][NJ] = {};
    for (int k0 = 0; k0 < K; k0 += 32){
        if (A_F32){
            f16x8v h0 = {}, h1 = {};
            if (rowA0 < M){
                float4 p = *(const float4*)(Af + (size_t)rowA0*K + k0 + ce);
                float4 q = *(const float4*)(Af + (size_t)rowA0*K + k0 + ce + 4);
                h0[0]=(f16)p.x; h0[1]=(f16)p.y; h0[2]=(f16)p.z; h0[3]=(f16)p.w;
                h0[4]=(f16)q.x; h0[5]=(f16)q.y; h0[6]=(f16)q.z; h0[7]=(f16)q.w;
            }
            if (rowA1 < M){
                float4 p = *(const float4*)(Af + (size_t)rowA1*K + k0 + ce);
                float4 q = *(const float4*)(Af + (size_t)rowA1*K + k0 + ce + 4);
                h1[0]=(f16)p.x; h1[1]=(f16)p.y; h1[2]=(f16)p.z; h1[3]=(f16)p.w;
                h1[4]=(f16)q.x; h1[5]=(f16)q.y; h1[6]=(f16)q.z; h1[7]=(f16)q.w;
            }
            *(f16x8v*)&As[tid*8]        = h0;
            *(f16x8v*)&As[tid*8 + 2048] = h1;
        } else {
            *(uint4*)&As[tid*8]        = *(const uint4*)(Ah + (size_t)rowA0*K + k0 + ce);
            *(uint4*)&As[tid*8 + 2048] = *(const uint4*)(Ah + (size_t)rowA1*K + k0 + ce);
        }
        *(uint4*)&Bs[tid*8] = *(const uint4*)(B0 + k0);
        if (BN == 128)
            *(uint4*)&Bs[tid*8 + 2048] = *(const uint4*)(B1 + k0);
        __syncthreads();
        f16x8v af[4], bf[NJ];
        #pragma unroll
        for (int i = 0; i < 4; ++i)
            af[i] = *(const f16x8v*)&As[(wm + i*16 + l15)*32 + quad*8];
        #pragma unroll
        for (int j = 0; j < NJ; ++j)
            bf[j] = *(const f16x8v*)&Bs[(wn + j*16 + l15)*32 + quad*8];
        #pragma unroll
        for (int i = 0; i < 4; ++i)
            #pragma unroll
            for (int j = 0; j < NJ; ++j)
                acc[i][j] = __builtin_amdgcn_mfma_f32_16x16x32_f16(af[i], bf[j], acc[i][j], 0, 0, 0);
        __syncthreads();
    }

    if (EPI == 2){
        float b4[NJ], w4[NJ];
        #pragma unroll
        for (int j = 0; j < NJ; ++j){
            int cg = n0 + wn + j*16 + l15;
            b4[j] = bias[cg]; w4[j] = Wh2[cg];
        }
        #pragma unroll
        for (int i = 0; i < 4; ++i)
            #pragma unroll
            for (int r = 0; r < 4; ++r){
                float ps = 0.f;
                #pragma unroll
                for (int j = 0; j < NJ; ++j){
                    float v = fmaxf(acc[i][j][r] + b4[j], 0.f);
                    ps = fmaf(v, w4[j], ps);
                }
                ps += __shfl_xor(ps, 1, 64); ps += __shfl_xor(ps, 2, 64);
                ps += __shfl_xor(ps, 4, 64); ps += __shfl_xor(ps, 8, 64);
                if (l15 == 0){
                    int row = m0 + wm + i*16 + quad*4 + r;
                    if (row < M) unsafeAtomicAdd(&logit[row], ps);
                }
            }
        return;
    }

    // store C (f16)
    #pragma unroll
    for (int i = 0; i < 4; ++i){
        int rb = m0 + wm + i*16 + quad*4;
        #pragma unroll
        for (int j = 0; j < NJ; ++j){
            int col = n0 + wn + j*16 + l15;
            float bv = HAS_BIAS ? bias[col] : 0.f;
            #pragma unroll
            for (int r = 0; r < 4; ++r){
                int row = rb + r;
                if (row >= M) continue;
                float v = acc[i][j][r] + bv;
                if (RELU) v = fmaxf(v, 0.f);
                ((f16*)C)[(size_t)row*N + col] = (f16)v;
            }
        }
    }

    if (EPI == 1){
        const int h = blockIdx.x;
        float ats[NJ], atd[NJ];
        #pragma unroll
        for (int j = 0; j < NJ; ++j){
            int c = wn + j*16 + l15;
            ats[j] = att_s[h*128 + c]; atd[j] = att_d[h*128 + c];
        }
        #pragma unroll
        for (int i = 0; i < 4; ++i)
            #pragma unroll
            for (int r = 0; r < 4; ++r){
                float ps = 0.f, pd = 0.f;
                #pragma unroll
                for (int j = 0; j < NJ; ++j){
                    float a = acc[i][j][r];
                    ps = fmaf(a, ats[j], ps); pd = fmaf(a, atd[j], pd);
                }
                ps += __shfl_xor(ps, 1, 64); ps += __shfl_xor(ps, 2, 64);
                ps += __shfl_xor(ps, 4, 64); ps += __shfl_xor(ps, 8, 64);
                pd += __shfl_xor(pd, 1, 64); pd += __shfl_xor(pd, 2, 64);
                pd += __shfl_xor(pd, 4, 64); pd += __shfl_xor(pd, 8, 64);
                if (l15 == 0){
                    int rl = wm + i*16 + quad*4 + r;
                    sred[0][rl][wn >> 6] = ps;
                    sred[1][rl][wn >> 6] = pd;
                }
            }
        __syncthreads();
        if (tid < 128){
            int row = m0 + tid;
            if (row < M){
                as_out[row*HEADS + h] = sred[0][tid][0] + sred[0][tid][1];
                ad_out[row*HEADS + h] = sred[1][tid][0] + sred[1][tid][1];
            }
        }
    }
}

// ---------- GCN aggregation (fp16 in/out, fp32 acc): fused self + bias + relu, 4-edge unroll ----------
template<int F>   // 256 or 128
__global__ __launch_bounds__(256) void gcn_agg_f16_k(const f16* __restrict__ h, const int* __restrict__ row_off,
        const int* __restrict__ srcs, const float* __restrict__ dinv, const float* __restrict__ bias,
        f16* __restrict__ out)
{
    int wv = (blockIdx.x*256 + threadIdx.x) >> 6;
    int lane = threadIdx.x & 63;
    if (wv >= NN) return;
    float di = dinv[wv];
    int p = row_off[wv], r1 = row_off[wv+1];
    if (F == 256){
        f16x4v v = *(const f16x4v*)(h + (size_t)wv*256 + lane*4);
        float c = di*di;
        float a0 = (float)v[0]*c, a1 = (float)v[1]*c, a2 = (float)v[2]*c, a3 = (float)v[3]*c;
        for (; p+4 <= r1; p += 4){
            int s0 = srcs[p], s1 = srcs[p+1], s2 = srcs[p+2], s3 = srcs[p+3];
            float c0 = dinv[s0]*di, c1 = dinv[s1]*di, c2 = dinv[s2]*di, c3 = dinv[s3]*di;
            f16x4v u0 = *(const f16x4v*)(h + (size_t)s0*256 + lane*4);
            f16x4v u1 = *(const f16x4v*)(h + (size_t)s1*256 + lane*4);
            f16x4v u2 = *(const f16x4v*)(h + (size_t)s2*256 + lane*4);
            f16x4v u3 = *(const f16x4v*)(h + (size_t)s3*256 + lane*4);
            a0 = fmaf((float)u3[0], c3, fmaf((float)u2[0], c2, fmaf((float)u1[0], c1, fmaf((float)u0[0], c0, a0))));
            a1 = fmaf((float)u3[1], c3, fmaf((float)u2[1], c2, fmaf((float)u1[1], c1, fmaf((float)u0[1], c0, a1))));
            a2 = fmaf((float)u3[2], c3, fmaf((float)u2[2], c2, fmaf((float)u1[2], c1, fmaf((float)u0[2], c0, a2))));
            a3 = fmaf((float)u3[3], c3, fmaf((float)u2[3], c2, fmaf((float)u1[3], c1, fmaf((float)u0[3], c0, a3))));
        }
        for (; p < r1; ++p){
            int s0 = srcs[p];
            float c0 = dinv[s0]*di;
            f16x4v u0 = *(const f16x4v*)(h + (size_t)s0*256 + lane*4);
            a0 = fmaf((float)u0[0], c0, a0); a1 = fmaf((float)u0[1], c0, a1);
            a2 = fmaf((float)u0[2], c0, a2); a3 = fmaf((float)u0[3], c0, a3);
        }
        float4 bv = *(const float4*)(bias + lane*4);
        f16x4v o;
        o[0] = (f16)fmaxf(a0 + bv.x, 0.f); o[1] = (f16)fmaxf(a1 + bv.y, 0.f);
        o[2] = (f16)fmaxf(a2 + bv.z, 0.f); o[3] = (f16)fmaxf(a3 + bv.w, 0.f);
        *(f16x4v*)(out + (size_t)wv*256 + lane*4) = o;
    } else {
        f16x2 v = *(const f16x2*)(h + (size_t)wv*128 + lane*2);
        float c = di*di;
        float a0 = (float)v[0]*c, a1 = (float)v[1]*c;
        for (; p+4 <= r1; p += 4){
            int s0 = srcs[p], s1 = srcs[p+1], s2 = srcs[p+2], s3 = srcs[p+3];
            float c0 = dinv[s0]*di, c1 = dinv[s1]*di, c2 = dinv[s2]*di, c3 = dinv[s3]*di;
            f16x2 u0 = *(const f16x2*)(h + (size_t)s0*128 + lane*2);
            f16x2 u1 = *(const f16x2*)(h + (size_t)s1*128 + lane*2);
            f16x2 u2 = *(const f16x2*)(h + (size_t)s2*128 + lane*2);
            f16x2 u3 = *(const f16x2*)(h + (size_t)s3*128 + lane*2);
            a0 = fmaf((float)u3[0], c3, fmaf((float)u2[0], c2, fmaf((float)u1[0], c1, fmaf((float)u0[0], c0, a0))));
            a1 = fmaf((float)u3[1], c3, fmaf((float)u2[1], c2, fmaf((float)u1[1], c1, fmaf((float)u0[1], c0, a1))));
        }
        for (; p < r1; ++p){
            int s0 = srcs[p];
            float c0 = dinv[s0]*di;
            f16x2 u0 = *(const f16x2*)(h + (size_t)s0*128 + lane*2);
            a0 = fmaf((float)u0[0], c0, a0); a1 = fmaf((float)u0[1], c0, a1);
        }
        float2 bv = *(const float2*)(bias + lane*2);
        f16x2 o;
        o[0] = (f16)fmaxf(a0 + bv.x, 0.f); o[1] = (f16)fmaxf(a1 + bv.y, 0.f);
        *(f16x2*)(out + (size_t)wv*128 + lane*2) = o;
    }
}

// ---------- GAT softmax over CSR ----------
__global__ __launch_bounds__(256) void gat_soft_k(const int* __restrict__ row_off, const int* __restrict__ srcs,
        const float* __restrict__ a_s, const float* __restrict__ a_d,
        float* __restrict__ ex_sorted, float* __restrict__ alpha_self, float* __restrict__ inv_den)
{
    int t = blockIdx.x*256 + threadIdx.x;
    if (t >= NN*HEADS) return;
    int d = t >> 3, h = t & 7;
    float ad = a_d[t];
    float eself = lrelu(a_s[t] + ad);
    float m = eself;
    int r0 = row_off[d], r1 = row_off[d+1];
    for (int p = r0; p < r1; ++p){
        int s = srcs[p];
        m = fmaxf(m, lrelu(a_s[s*HEADS + h] + ad));
    }
    float den = expf(eself - m);
    for (int p = r0; p < r1; ++p){
        int s = srcs[p];
        float x = expf(lrelu(a_s[s*HEADS + h] + ad) - m);
        ex_sorted[(size_t)p*HEADS + h] = x;
        den += x;
    }
    float id = 1.f / den;
    alpha_self[t] = expf(eself - m) * id;
    inv_den[t]    = id;
}
// per (dst, half): gat[d, half*512 + :512] — 2 waves per node, 4-edge unroll
__global__ __launch_bounds__(256) void gat_out_f16_k(const f16* __restrict__ hg, const int* __restrict__ row_off,
        const int* __restrict__ srcs, const float* __restrict__ exs, const float* __restrict__ aself,
        const float* __restrict__ idn, const float* __restrict__ bg, f16* __restrict__ gat)
{
    int gw = (blockIdx.x*256 + threadIdx.x) >> 6;   // over 2*NN
    int lane = threadIdx.x & 63;
    int node = gw >> 1;
    if (node >= NN) return;
    int colbase = (gw & 1)*512 + lane*8;
    int hh = colbase >> 7;
    int nh = node*HEADS + hh;
    float as = aself[nh];
    float id = idn[nh];
    const f16* table = hg + colbase;
    f16x8v v = *(const f16x8v*)(table + (size_t)node*GDIM);
    float acc[8];
    #pragma unroll
    for (int q = 0; q < 8; ++q) acc[q] = (float)v[q]*as;
    int p = row_off[node], r1 = row_off[node+1];
    for (; p+4 <= r1; p += 4){
        int s0 = srcs[p], s1 = srcs[p+1], s2 = srcs[p+2], s3 = srcs[p+3];
        float al0 = exs[(size_t)p*HEADS + hh] * id;
        float al1 = exs[(size_t)(p+1)*HEADS + hh] * id;
        float al2 = exs[(size_t)(p+2)*HEADS + hh] * id;
        float al3 = exs[(size_t)(p+3)*HEADS + hh] * id;
        f16x8v u0 = *(const f16x8v*)(table + (size_t)s0*GDIM);
        f16x8v u1 = *(const f16x8v*)(table + (size_t)s1*GDIM);
        f16x8v u2 = *(const f16x8v*)(table + (size_t)s2*GDIM);
        f16x8v u3 = *(const f16x8v*)(table + (size_t)s3*GDIM);
        #pragma unroll
        for (int q = 0; q < 8; ++q)
            acc[q] = fmaf((float)u3[q], al3, fmaf((float)u2[q], al2,
                     fmaf((float)u1[q], al1, fmaf((float)u0[q], al0, acc[q]))));
    }
    for (; p < r1; ++p){
        int s0 = srcs[p];
        float al0 = exs[(size_t)p*HEADS + hh] * id;
        f16x8v u0 = *(const f16x8v*)(table + (size_t)s0*GDIM);
        #pragma unroll
        for (int q = 0; q < 8; ++q) acc[q] = fmaf((float)u0[q], al0, acc[q]);
    }
    float4 b0 = *(const float4*)(bg + colbase);
    float4 b1 = *(const float4*)(bg + colbase + 4);
    f16x8v o;
    o[0]=(f16)(acc[0]+b0.x); o[1]=(f16)(acc[1]+b0.y); o[2]=(f16)(acc[2]+b0.z); o[3]=(f16)(acc[3]+b0.w);
    o[4]=(f16)(acc[4]+b1.x); o[5]=(f16)(acc[5]+b1.y); o[6]=(f16)(acc[6]+b1.z); o[7]=(f16)(acc[7]+b1.w);
    *(f16x8v*)(gat + (size_t)node*GDIM + colbase) = o;
}

// ---------- head: sigmoid + global exp-sum (no max pass needed: w in (0,1)) ----------
__global__ __launch_bounds__(256) void head_sum_k(const float* __restrict__ logit, const float* __restrict__ bh2,
                                                  float* __restrict__ w, float* __restrict__ red){
    __shared__ float sm[256];
    int i = blockIdx.x*256 + threadIdx.x;
    float v = 0.f;
    if (i < NN){
        float s = 1.f / (1.f + expf(-(logit[i] + bh2[0])));
        w[i] = s;
        v = expf(s);
    }
    sm[threadIdx.x] = v; __syncthreads();
    for (int off = 128; off; off >>= 1){
        if (threadIdx.x < off) sm[threadIdx.x] += sm[threadIdx.x+off];
        __syncthreads();
    }
    if (!threadIdx.x) unsafeAtomicAdd(&red[0], sm[0]);
}
__global__ __launch_bounds__(256) void final_k(const float* __restrict__ w, const float* __restrict__ red,
                                               float* __restrict__ out){
    int i = blockIdx.x*256 + threadIdx.x;
    if (i >= NN) return;
    out[i] = expf(w[i]) / red[0];
}

// ---------- launch ----------
extern "C" void kernel_launch(void* const* d_in, const int* in_sizes, int n_in,
                              void* d_out, int out_size, void* d_ws, size_t ws_size,
                              hipStream_t stream) {
    const float* x   = (const float*)d_in[0];
    const int*   ei  = (const int*)  d_in[1];
    const float* W1  = (const float*)d_in[2];
    const float* b1  = (const float*)d_in[3];
    const float* W2  = (const float*)d_in[4];
    const float* b2  = (const float*)d_in[5];
    const float* W3  = (const float*)d_in[6];
    const float* b3  = (const float*)d_in[7];
    const float* Wg  = (const float*)d_in[8];
    const float* att_src = (const float*)d_in[9];
    const float* att_dst = (const float*)d_in[10];
    const float* bg  = (const float*)d_in[11];
    const float* Wh1 = (const float*)d_in[12];
    const float* bh1 = (const float*)d_in[13];
    const float* Wh2 = (const float*)d_in[14];
    const float* bh2 = (const float*)d_in[15];
    float* out = (float*)d_out;

    const int E = in_sizes[1] / 2;
    const int* src = ei;
    const int* dst = ei + E;

    float* ws = (float*)d_ws;
    size_t o = 0;
    auto alloc = [&](size_t nfloats){ float* p = ws + o; o += (nfloats + 3) & ~(size_t)3; return p; };
    // zero region: cnt, cursor, logit, red contiguous
    int* cnt    = (int*)alloc(NN);
    int* cursor = (int*)alloc(NN);
    float* logit= alloc(NN);
    float* red  = alloc(8);
    const int ZERO_N = 3*NN + 8;

    f16* wt1   = (f16*)alloc(65536/2);
    f16* wt2   = (f16*)alloc(65536/2);
    f16* wt3   = (f16*)alloc(32768/2);
    f16* wtg   = (f16*)alloc(131072/2);
    f16* wth1  = (f16*)alloc(262144/2);
    f16* fH    = (f16*)alloc((size_t)M_PAD*256/2);
    f16* fG    = (f16*)alloc((size_t)M_PAD*256/2);
    f16* hg    = (f16*)alloc((size_t)M_PAD*GDIM/2);
    f16* gat   = (f16*)alloc((size_t)M_PAD*GDIM/2);
    float* dinv = alloc(NN);
    float* a_s  = alloc((size_t)NN*HEADS);
    float* a_d  = alloc((size_t)NN*HEADS);
    float* aself= alloc((size_t)NN*HEADS);
    float* idn  = alloc((size_t)NN*HEADS);
    float* exs  = alloc((size_t)E*HEADS);
    float* wsig = alloc(NN);
    int* row_off= (int*)alloc(NN+1);
    int* src_srt= (int*)alloc(E);

    const int nb  = (NN + 255)/256;
    const int eb  = (E + 255)/256;
    const int nwb = (NN + 3)/4;
    const dim3 blk(256);
    const int MT = M_PAD/128;   // 157

    // init (zero + weight cvt), CSR, dinv
    const int INIT_T = ZERO_N + 65536*2 + 32768 + 131072 + 262144;
    init_k<<<(INIT_T + 255)/256, blk, 0, stream>>>(cnt, ZERO_N, W1, W2, W3, Wg, Wh1,
                                                   wt1, wt2, wt3, wtg, wth1);
    hist_k<<<eb, blk, 0, stream>>>(dst, cnt, E);
    scan_k<<<1, 1024, 0, stream>>>(cnt, row_off, dinv);
    scatter_k<<<eb, blk, 0, stream>>>(src, dst, row_off, cursor, src_srt, E);

    // GCN 1: A = x (fp32, read directly)  [BN=64: 4x157 blocks]
    gemm_f16_k<0,64,true,false,false><<<dim3(4, MT), blk, 0, stream>>>(
        x, wt1, nullptr, fH, nullptr, nullptr, nullptr, nullptr, nullptr, nullptr, NN, 256, 256);
    gcn_agg_f16_k<256><<<nwb, blk, 0, stream>>>(fH, row_off, src_srt, dinv, b1, fG);
    // GCN 2
    gemm_f16_k<0,64,false,false,false><<<dim3(4, MT), blk, 0, stream>>>(
        fG, wt2, nullptr, fH, nullptr, nullptr, nullptr, nullptr, nullptr, nullptr, NN, 256, 256);
    gcn_agg_f16_k<256><<<nwb, blk, 0, stream>>>(fH, row_off, src_srt, dinv, b2, fG);
    // GCN 3 (N=128)
    gemm_f16_k<0,64,false,false,false><<<dim3(2, MT), blk, 0, stream>>>(
        fG, wt3, nullptr, fH, nullptr, nullptr, nullptr, nullptr, nullptr, nullptr, NN, 128, 256);
    gcn_agg_f16_k<128><<<nwb, blk, 0, stream>>>(fH, row_off, src_srt, dinv, b3, fG);

    // GAT projection (K=128, N=1024) + fused att dots  [BN=128: 8x157 blocks]
    gemm_f16_k<1,128,false,false,false><<<dim3(8, MT), blk, 0, stream>>>(
        fG, wtg, nullptr, hg, att_src, att_dst, a_s, a_d, nullptr, nullptr, NN, 1024, 128);
    gat_soft_k<<<(NN*HEADS)/256, blk, 0, stream>>>(row_off, src_srt, a_s, a_d, exs, aself, idn);
    gat_out_f16_k<<<NN/2, blk, 0, stream>>>(hg, row_off, src_srt, exs, aself, idn, bg, gat);

    // head MLP (K=1024, N=256): fused relu(z)@Wh2 -> logit atomics  [BN=64: 628 blocks, full K]
    gemm_f16_k<2,64,false,true,true><<<dim3(4, MT), blk, 0, stream>>>(
        gat, wth1, bh1, nullptr, nullptr, nullptr, nullptr, nullptr, Wh2, logit, NN, 256, 1024);

    // sigmoid + global softmax (no max pass: w bounded in (0,1))
    head_sum_k<<<nb, blk, 0, stream>>>(logit, bh2, wsig, red);
    final_k<<<nb, blk, 0, stream>>>(wsig, red, out);
}